// Round 3
// baseline (257.846 us; speedup 1.0000x reference)
//
#include <hip/hip_runtime.h>
#include <stdint.h>

// ksparse: per row of 4096x8192 f32, threshold = 513th largest (k=512),
// out = x * (x > thresh). Exact radix-select on the order-preserving uint32
// mapping. v4 (after v2/v3 spill post-mortem: NEVER grow per-thread state):
//  - TPB=512, 16 elems/thread (v[4] float4 = 16 data VGPRs, half of v1),
//    __launch_bounds__(512,8) -> 4 blocks x 8 waves = 32 waves/CU resident.
//  - no m[] array: histogram bin computed from raw bits (bin11 == map>>21,
//    proven identity); full map only for ~220 candidates; final mask is a
//    FLOAT compare x > unmap(T) (== reference's strict float >).
//  - 5 barriers/row (was 11): pass-0 scan and all 3 tail passes run entirely
//    in wave 0 (ballot/shfl/ds, no block syncs between tail passes).
//  - loads issued AFTER B1 so no barrier drains vmcnt against them (the
//    gfx950 compiler emits s_waitcnt vmcnt(0) before every s_barrier).
//  - hist layout XOR-swizzled at quad granularity so wave0's contiguous
//    32-bins/lane scan (ds_read_b128, lane stride 128B) is conflict-free.

constexpr int COLS  = 8192;
constexpr int TPB   = 512;
constexpr int EPT   = COLS / TPB;   // 16 elements per thread
constexpr int VPT   = EPT / 4;      // 4 float4 per thread
constexpr int NBIN0 = 2048;         // pass-0 bins (11 bits)
constexpr int CAP   = 2048;         // candidate buffer (reuses replica 1)

__device__ __forceinline__ uint32_t map_f32(uint32_t u) {
  return (u & 0x80000000u) ? ~u : (u | 0x80000000u);
}
__device__ __forceinline__ float unmap_f32(uint32_t m) {
  return __uint_as_float((m & 0x80000000u) ? (m ^ 0x80000000u) : ~m);
}
// Top-11 bits of map_f32(u), without materializing the map:
// positive: (u>>21)|0x400 ; negative: 0x7FF - (u>>21) == 0x7FF ^ (u>>21).
__device__ __forceinline__ uint32_t bin11(uint32_t u) {
  const uint32_t s = u >> 21;
  return (u & 0x80000000u) ? (0x7FFu ^ s) : (s | 0x400u);
}
// Word-index swizzle within a 2048-bin replica: XOR quad-index bits (2..4)
// with lane bits (5..7). Bijective, preserves 16B alignment, spreads the
// scan's lane-stride-128B reads across all 32 banks.
__device__ __forceinline__ uint32_t hswz(uint32_t w) {
  return w ^ ((w >> 3) & 0x1Cu);
}

__global__ __launch_bounds__(TPB, 8)
void ksparse_kernel(const float* __restrict__ in, const int* __restrict__ kptr,
                    float* __restrict__ out) {
  __shared__ __align__(16) uint32_t hist[2 * NBIN0]; // 16KB: rep0 | rep1 (-> cand)
  __shared__ uint32_t th[3 * 128];                   // tail histograms
  __shared__ uint32_t s_packed;                      // (d0<<14)|above from pass 0
  __shared__ uint32_t s_cnt;                         // candidate count
  __shared__ uint32_t s_T;                           // final mapped threshold

  const int t    = threadIdx.x;
  const int wave = t >> 6;
  const int lane = t & 63;
  const size_t rowbase = (size_t)blockIdx.x * COLS;

  // ---- zero LDS FIRST, then barrier, THEN issue loads: the barrier has no
  // outstanding vmem to drain, and each wave stalls only on its own loads ----
  uint4* h4 = (uint4*)hist;
  h4[t] = make_uint4(0u, 0u, 0u, 0u);                // 512 x 16B = 8KB
  h4[t + TPB] = make_uint4(0u, 0u, 0u, 0u);          // next 8KB
  if (t < 384) th[t] = 0u;
  if (t == 0) { s_packed = 0u; s_cnt = 0u; }
  const uint32_t kbase = (uint32_t)(*kptr) + 1u;     // rank from top: 513th largest
  __syncthreads(); // B1: zeroing done (no vmem in flight)

  // ---- issue loads; map+histogram interleaves under vmcnt counting ----
  const float4* inp = (const float4*)(in + rowbase);
  float4 v[VPT];
#pragma unroll
  for (int i = 0; i < VPT; ++i) v[i] = inp[t + i * TPB];

  uint32_t* h = &hist[(wave >> 2) * NBIN0]; // waves 0-3 -> rep0, 4-7 -> rep1
#pragma unroll
  for (int i = 0; i < VPT; ++i) {
    atomicAdd(&h[hswz(bin11(__float_as_uint(v[i].x)))], 1u);
    atomicAdd(&h[hswz(bin11(__float_as_uint(v[i].y)))], 1u);
    atomicAdd(&h[hswz(bin11(__float_as_uint(v[i].z)))], 1u);
    atomicAdd(&h[hswz(bin11(__float_as_uint(v[i].w)))], 1u);
  }
  __syncthreads(); // B2: histogram done

  // ---- pass-0 scan entirely in wave 0: lane owns bins [32*lane, 32*lane+32) ----
  if (wave == 0) {
    const uint4* r0 = (const uint4*)&hist[0];
    const uint4* r1 = (const uint4*)&hist[NBIN0];
    uint32_t qs[8]; // per-quad (4-bin) sums
    uint32_t total = 0;
#pragma unroll
    for (int q = 0; q < 8; ++q) {
      const uint32_t Q = (uint32_t)(8 * lane + q);
      const uint32_t Qs = Q ^ (uint32_t)(lane & 7); // swizzled quad index
      const uint4 a = r0[Qs];
      const uint4 b = r1[Qs];
      qs[q] = (a.x + b.x) + (a.y + b.y) + (a.z + b.z) + (a.w + b.w);
      total += qs[q];
    }
    // inclusive suffix over lanes: s = sum of totals for lanes >= lane
    uint32_t s = total;
#pragma unroll
    for (int off = 1; off < 64; off <<= 1) {
      const uint32_t tmp = __shfl_down(s, off, 64);
      s += (lane + off < 64) ? tmp : 0u;
    }
    const unsigned long long mb = __ballot(s >= kbase); // lanes 0..l* set; l0 always
    const int lstar = 63 - __builtin_clzll(mb);
    if (lane == lstar) {
      // find largest quad q with (count above quad q) + qs[q] >= kbase
      uint32_t run = s - total; // count in bins above my range
      int qq = -1; uint32_t qab = 0;
#pragma unroll
      for (int q = 7; q >= 0; --q) {
        const uint32_t nrun = run + qs[q];
        if (qq < 0 && nrun >= kbase) { qq = q; qab = run; }
        run = nrun;
      }
      // resolve element within the quad (re-read that quad; 1 lane active)
      const uint32_t Qs = (uint32_t)(8 * lane + qq) ^ (uint32_t)(lane & 7);
      const uint4 a = r0[Qs];
      const uint4 b = r1[Qs];
      const uint32_t c0 = a.x + b.x, c1 = a.y + b.y, c2 = a.z + b.z, c3 = a.w + b.w;
      const uint32_t s3 = qab + c3;
      const uint32_t s2 = s3 + c2, s1 = s2 + c1;
      uint32_t e, above;
      if (s3 >= kbase)      { e = 3u; above = qab; }
      else if (s2 >= kbase) { e = 2u; above = s3; }
      else if (s1 >= kbase) { e = 1u; above = s2; }
      else                  { e = 0u; above = s1; }
      const uint32_t d0 = (uint32_t)(lane * 32 + qq * 4) + e;
      s_packed = (d0 << 14) | above; // above < kbase <= 16383, fits 14 bits
    }
  }
  __syncthreads(); // B3: d0 published

  const uint32_t pk = s_packed;
  const uint32_t d0 = pk >> 14;

  // ---- compact candidates (bin == d0) into dead replica-1 LDS ----
  uint32_t* cand = &hist[NBIN0];
#pragma unroll
  for (int i = 0; i < VPT; ++i) {
    uint32_t u;
    u = __float_as_uint(v[i].x);
    if (bin11(u) == d0) { const uint32_t x = atomicAdd(&s_cnt, 1u); if (x < CAP) cand[x] = map_f32(u) & 0x1FFFFFu; }
    u = __float_as_uint(v[i].y);
    if (bin11(u) == d0) { const uint32_t x = atomicAdd(&s_cnt, 1u); if (x < CAP) cand[x] = map_f32(u) & 0x1FFFFFu; }
    u = __float_as_uint(v[i].z);
    if (bin11(u) == d0) { const uint32_t x = atomicAdd(&s_cnt, 1u); if (x < CAP) cand[x] = map_f32(u) & 0x1FFFFFu; }
    u = __float_as_uint(v[i].w);
    if (bin11(u) == d0) { const uint32_t x = atomicAdd(&s_cnt, 1u); if (x < CAP) cand[x] = map_f32(u) & 0x1FFFFFu; }
  }
  __syncthreads(); // B4: compaction done

  // ---- three 7-bit tail passes, entirely in wave 0 (no block barriers) ----
  if (wave == 0) {
    const uint32_t Cc = (s_cnt < (uint32_t)CAP) ? s_cnt : (uint32_t)CAP;
    uint32_t kk = kbase - (pk & 0x3FFFu);
    uint32_t tpref = 0;
#pragma unroll 1
    for (int j = 0; j < 3; ++j) {
      const int dsh = 14 - 7 * j;
      uint32_t* thj = &th[j * 128];
      for (uint32_t idx = (uint32_t)lane; idx < Cc; idx += 64u) {
        const uint32_t c = cand[idx];
        const bool ok = (j == 0) || ((c >> (dsh + 7)) == tpref);
        if (ok) atomicAdd(&thj[(c >> dsh) & 127u], 1u);
      }
      // same-wave ds ordering: compiler inserts lgkmcnt before these reads
      const uint32_t a = thj[lane], b = thj[64 + lane];
      uint32_t sb = b, sa = a;
#pragma unroll
      for (int off = 1; off < 64; off <<= 1) {
        const uint32_t t1 = __shfl_down(sb, off, 64);
        const uint32_t t2 = __shfl_down(sa, off, 64);
        const bool inr = (lane + off < 64);
        sb += inr ? t1 : 0u;
        sa += inr ? t2 : 0u;
      }
      const uint32_t tb = __shfl(sb, 0, 64); // total of bins 64..127
      sa += tb;
      const unsigned long long mbj = __ballot(sb >= kk);
      uint32_t d, ab;
      if (mbj) {
        const int hb = 63 - __builtin_clzll(mbj);
        const uint32_t nx = __shfl(sb, (hb + 1) & 63, 64);
        d = 64u + (uint32_t)hb;
        ab = (hb == 63) ? 0u : nx;
      } else {
        const unsigned long long ma = __ballot(sa >= kk); // nonzero by invariant
        const int ha = 63 - __builtin_clzll(ma);
        const uint32_t nx = __shfl(sa, (ha + 1) & 63, 64);
        d = (uint32_t)ha;
        ab = (ha == 63) ? tb : nx;
      }
      tpref = (tpref << 7) | d;
      kk -= ab;
    }
    if (lane == 0) s_T = (d0 << 21) | tpref; // exact mapped bits of rank-(k+1)
  }
  __syncthreads(); // B5: threshold published

  // ---- masked write with FLOAT compare (== reference's strict >) ----
  const float thr = unmap_f32(s_T);
  float4* op = (float4*)(out + rowbase);
#pragma unroll
  for (int i = 0; i < VPT; ++i) {
    float4 w;
    w.x = (v[i].x > thr) ? v[i].x : 0.0f;
    w.y = (v[i].y > thr) ? v[i].y : 0.0f;
    w.z = (v[i].z > thr) ? v[i].z : 0.0f;
    w.w = (v[i].w > thr) ? v[i].w : 0.0f;
    op[t + i * TPB] = w;
  }
}

extern "C" void kernel_launch(void* const* d_in, const int* in_sizes, int n_in,
                              void* d_out, int out_size, void* d_ws, size_t ws_size,
                              hipStream_t stream) {
  const float* in  = (const float*)d_in[0];
  const int*   k   = (const int*)d_in[1];
  float*       out = (float*)d_out;
  int rows = in_sizes[0] / COLS;
  if (rows < 1) rows = 1;
  ksparse_kernel<<<rows, TPB, 0, stream>>>(in, k, out);
}

// Round 4
// 235.963 us; speedup vs baseline: 1.0927x; 1.0927x over previous
//
#include <hip/hip_runtime.h>
#include <stdint.h>

// ksparse: per row of 4096x8192 f32, threshold = 513th largest (k=512),
// out = x * (x > thresh). Exact radix-select on the order-preserving uint32
// mapping. v5 = v4 structure with the spill fixed:
//  - TPB=512, 16 elems/thread (v[4] float4 = 16 data VGPRs).
//    __launch_bounds__(512, 4): VGPR cap 128, demand ~48-56 -> NO SPILL
//    (v4's (512,8) forced 32 VGPRs and spilled one float4/thread: WRITE_SIZE
//    167936 vs 131072 KB. Lesson: cap must exceed live-state demand.)
//    At <=64 VGPRs the HW still resides 8 waves/SIMD -> ~77% occupancy kept.
//  - no m[] array: histogram bin computed from raw bits (bin11 == map>>21,
//    proven identity); full map only for ~220 candidates; final mask is a
//    FLOAT compare x > unmap(T) (== reference's strict float >, harness-
//    verified absmax=0 in v4).
//  - 5 barriers/row (v1 had 11): pass-0 scan and all 3 tail passes run
//    entirely in wave 0 (ballot/shfl, no block syncs between tail passes).
//  - loads issued AFTER B1 so no barrier drains vmcnt against them (gfx950
//    compiler emits s_waitcnt vmcnt(0) before every s_barrier).
//  - hist layout XOR-swizzled at quad granularity so wave0's contiguous
//    32-bins/lane scan is bank-conflict-free (minor; conflicts measured
//    negligible at ~0.5us/dispatch).

constexpr int COLS  = 8192;
constexpr int TPB   = 512;
constexpr int EPT   = COLS / TPB;   // 16 elements per thread
constexpr int VPT   = EPT / 4;      // 4 float4 per thread
constexpr int NBIN0 = 2048;         // pass-0 bins (11 bits)
constexpr int CAP   = 2048;         // candidate buffer (reuses replica 1)

__device__ __forceinline__ uint32_t map_f32(uint32_t u) {
  return (u & 0x80000000u) ? ~u : (u | 0x80000000u);
}
__device__ __forceinline__ float unmap_f32(uint32_t m) {
  return __uint_as_float((m & 0x80000000u) ? (m ^ 0x80000000u) : ~m);
}
// Top-11 bits of map_f32(u), without materializing the map:
// positive: (u>>21)|0x400 ; negative: 0x7FF ^ (u>>21).
__device__ __forceinline__ uint32_t bin11(uint32_t u) {
  const uint32_t s = u >> 21;
  return (u & 0x80000000u) ? (0x7FFu ^ s) : (s | 0x400u);
}
// Word-index swizzle within a 2048-bin replica: XOR quad-index bits (2..4)
// with lane bits (5..7). Bijective, preserves 16B alignment.
__device__ __forceinline__ uint32_t hswz(uint32_t w) {
  return w ^ ((w >> 3) & 0x1Cu);
}

__global__ __launch_bounds__(TPB, 4)
void ksparse_kernel(const float* __restrict__ in, const int* __restrict__ kptr,
                    float* __restrict__ out) {
  __shared__ __align__(16) uint32_t hist[2 * NBIN0]; // 16KB: rep0 | rep1 (-> cand)
  __shared__ uint32_t th[3 * 128];                   // tail histograms
  __shared__ uint32_t s_packed;                      // (d0<<14)|above from pass 0
  __shared__ uint32_t s_cnt;                         // candidate count
  __shared__ uint32_t s_T;                           // final mapped threshold

  const int t    = threadIdx.x;
  const int wave = t >> 6;
  const int lane = t & 63;
  const size_t rowbase = (size_t)blockIdx.x * COLS;

  // ---- zero LDS FIRST, then barrier, THEN issue loads: the barrier has no
  // outstanding vmem to drain, and each wave stalls only on its own loads ----
  uint4* h4 = (uint4*)hist;
  h4[t] = make_uint4(0u, 0u, 0u, 0u);                // 512 x 16B = 8KB
  h4[t + TPB] = make_uint4(0u, 0u, 0u, 0u);          // next 8KB
  if (t < 384) th[t] = 0u;
  if (t == 0) { s_packed = 0u; s_cnt = 0u; }
  const uint32_t kbase = (uint32_t)(*kptr) + 1u;     // rank from top: 513th largest
  __syncthreads(); // B1: zeroing done (no vmem in flight)

  // ---- issue loads; map+histogram interleaves under vmcnt counting ----
  const float4* inp = (const float4*)(in + rowbase);
  float4 v[VPT];
#pragma unroll
  for (int i = 0; i < VPT; ++i) v[i] = inp[t + i * TPB];

  uint32_t* h = &hist[(wave >> 2) * NBIN0]; // waves 0-3 -> rep0, 4-7 -> rep1
#pragma unroll
  for (int i = 0; i < VPT; ++i) {
    atomicAdd(&h[hswz(bin11(__float_as_uint(v[i].x)))], 1u);
    atomicAdd(&h[hswz(bin11(__float_as_uint(v[i].y)))], 1u);
    atomicAdd(&h[hswz(bin11(__float_as_uint(v[i].z)))], 1u);
    atomicAdd(&h[hswz(bin11(__float_as_uint(v[i].w)))], 1u);
  }
  __syncthreads(); // B2: histogram done

  // ---- pass-0 scan entirely in wave 0: lane owns bins [32*lane, 32*lane+32) ----
  if (wave == 0) {
    const uint4* r0 = (const uint4*)&hist[0];
    const uint4* r1 = (const uint4*)&hist[NBIN0];
    uint32_t qs[8]; // per-quad (4-bin) sums
    uint32_t total = 0;
#pragma unroll
    for (int q = 0; q < 8; ++q) {
      const uint32_t Q = (uint32_t)(8 * lane + q);
      const uint32_t Qs = Q ^ (uint32_t)(lane & 7); // swizzled quad index
      const uint4 a = r0[Qs];
      const uint4 b = r1[Qs];
      qs[q] = (a.x + b.x) + (a.y + b.y) + (a.z + b.z) + (a.w + b.w);
      total += qs[q];
    }
    // inclusive suffix over lanes: s = sum of totals for lanes >= lane
    uint32_t s = total;
#pragma unroll
    for (int off = 1; off < 64; off <<= 1) {
      const uint32_t tmp = __shfl_down(s, off, 64);
      s += (lane + off < 64) ? tmp : 0u;
    }
    const unsigned long long mb = __ballot(s >= kbase); // lanes 0..l* set; l0 always
    const int lstar = 63 - __builtin_clzll(mb);
    if (lane == lstar) {
      // find largest quad q with (count above quad q) + qs[q] >= kbase
      uint32_t run = s - total; // count in bins above my range
      int qq = -1; uint32_t qab = 0;
#pragma unroll
      for (int q = 7; q >= 0; --q) {
        const uint32_t nrun = run + qs[q];
        if (qq < 0 && nrun >= kbase) { qq = q; qab = run; }
        run = nrun;
      }
      // resolve element within the quad (re-read that quad; 1 lane active)
      const uint32_t Qs = (uint32_t)(8 * lane + qq) ^ (uint32_t)(lane & 7);
      const uint4 a = r0[Qs];
      const uint4 b = r1[Qs];
      const uint32_t c1 = a.y + b.y, c2 = a.z + b.z, c3 = a.w + b.w;
      const uint32_t s3 = qab + c3;
      const uint32_t s2 = s3 + c2, s1 = s2 + c1;
      uint32_t e, above;
      if (s3 >= kbase)      { e = 3u; above = qab; }
      else if (s2 >= kbase) { e = 2u; above = s3; }
      else if (s1 >= kbase) { e = 1u; above = s2; }
      else                  { e = 0u; above = s1; }
      const uint32_t d0 = (uint32_t)(lane * 32 + qq * 4) + e;
      s_packed = (d0 << 14) | above; // above < kbase <= 16383, fits 14 bits
    }
  }
  __syncthreads(); // B3: d0 published

  const uint32_t pk = s_packed;
  const uint32_t d0 = pk >> 14;

  // ---- compact candidates (bin == d0) into dead replica-1 LDS ----
  uint32_t* cand = &hist[NBIN0];
#pragma unroll
  for (int i = 0; i < VPT; ++i) {
    uint32_t u;
    u = __float_as_uint(v[i].x);
    if (bin11(u) == d0) { const uint32_t x = atomicAdd(&s_cnt, 1u); if (x < CAP) cand[x] = map_f32(u) & 0x1FFFFFu; }
    u = __float_as_uint(v[i].y);
    if (bin11(u) == d0) { const uint32_t x = atomicAdd(&s_cnt, 1u); if (x < CAP) cand[x] = map_f32(u) & 0x1FFFFFu; }
    u = __float_as_uint(v[i].z);
    if (bin11(u) == d0) { const uint32_t x = atomicAdd(&s_cnt, 1u); if (x < CAP) cand[x] = map_f32(u) & 0x1FFFFFu; }
    u = __float_as_uint(v[i].w);
    if (bin11(u) == d0) { const uint32_t x = atomicAdd(&s_cnt, 1u); if (x < CAP) cand[x] = map_f32(u) & 0x1FFFFFu; }
  }
  __syncthreads(); // B4: compaction done

  // ---- three 7-bit tail passes, entirely in wave 0 (no block barriers) ----
  if (wave == 0) {
    const uint32_t Cc = (s_cnt < (uint32_t)CAP) ? s_cnt : (uint32_t)CAP;
    uint32_t kk = kbase - (pk & 0x3FFFu);
    uint32_t tpref = 0;
#pragma unroll 1
    for (int j = 0; j < 3; ++j) {
      const int dsh = 14 - 7 * j;
      uint32_t* thj = &th[j * 128];
      for (uint32_t idx = (uint32_t)lane; idx < Cc; idx += 64u) {
        const uint32_t c = cand[idx];
        const bool ok = (j == 0) || ((c >> (dsh + 7)) == tpref);
        if (ok) atomicAdd(&thj[(c >> dsh) & 127u], 1u);
      }
      // same-wave ds ordering: compiler inserts lgkmcnt before these reads
      const uint32_t a = thj[lane], b = thj[64 + lane];
      uint32_t sb = b, sa = a;
#pragma unroll
      for (int off = 1; off < 64; off <<= 1) {
        const uint32_t t1 = __shfl_down(sb, off, 64);
        const uint32_t t2 = __shfl_down(sa, off, 64);
        const bool inr = (lane + off < 64);
        sb += inr ? t1 : 0u;
        sa += inr ? t2 : 0u;
      }
      const uint32_t tb = __shfl(sb, 0, 64); // total of bins 64..127
      sa += tb;
      const unsigned long long mbj = __ballot(sb >= kk);
      uint32_t d, ab;
      if (mbj) {
        const int hb = 63 - __builtin_clzll(mbj);
        const uint32_t nx = __shfl(sb, (hb + 1) & 63, 64);
        d = 64u + (uint32_t)hb;
        ab = (hb == 63) ? 0u : nx;
      } else {
        const unsigned long long ma = __ballot(sa >= kk); // nonzero by invariant
        const int ha = 63 - __builtin_clzll(ma);
        const uint32_t nx = __shfl(sa, (ha + 1) & 63, 64);
        d = (uint32_t)ha;
        ab = (ha == 63) ? tb : nx;
      }
      tpref = (tpref << 7) | d;
      kk -= ab;
    }
    if (lane == 0) s_T = (d0 << 21) | tpref; // exact mapped bits of rank-(k+1)
  }
  __syncthreads(); // B5: threshold published

  // ---- masked write with FLOAT compare (== reference's strict >) ----
  const float thr = unmap_f32(s_T);
  float4* op = (float4*)(out + rowbase);
#pragma unroll
  for (int i = 0; i < VPT; ++i) {
    float4 w;
    w.x = (v[i].x > thr) ? v[i].x : 0.0f;
    w.y = (v[i].y > thr) ? v[i].y : 0.0f;
    w.z = (v[i].z > thr) ? v[i].z : 0.0f;
    w.w = (v[i].w > thr) ? v[i].w : 0.0f;
    op[t + i * TPB] = w;
  }
}

extern "C" void kernel_launch(void* const* d_in, const int* in_sizes, int n_in,
                              void* d_out, int out_size, void* d_ws, size_t ws_size,
                              hipStream_t stream) {
  const float* in  = (const float*)d_in[0];
  const int*   k   = (const int*)d_in[1];
  float*       out = (float*)d_out;
  int rows = in_sizes[0] / COLS;
  if (rows < 1) rows = 1;
  ksparse_kernel<<<rows, TPB, 0, stream>>>(in, k, out);
}